// Round 2
// baseline (40504.962 us; speedup 1.0000x reference)
//
#include <hip/hip_runtime.h>
#include <cstdint>
#include <cstddef>

typedef unsigned short u16;
typedef unsigned int   u32;

#define Bn 4
#define Tn 512
#define Hn 512
#define En 256
#define Vn 50257
#define NPAD 50304

#define RG  128
#define RNT 256

__device__ __forceinline__ u16 f2bf(float f) {
  u32 x; __builtin_memcpy(&x, &f, 4);
  u32 r = (x + 0x7fffu + ((x >> 16) & 1u)) >> 16;
  return (u16)r;
}

// device-scope grid barrier (all RG blocks co-resident)
__device__ __forceinline__ void gbar(u32* cnt, unsigned& ep) {
  __syncthreads();
  if (threadIdx.x == 0) {
    ++ep;
    __hip_atomic_fetch_add(cnt, 1u, __ATOMIC_RELEASE, __HIP_MEMORY_SCOPE_AGENT);
    const unsigned tgt = ep * (unsigned)RG;
    while (__hip_atomic_load(cnt, __ATOMIC_RELAXED, __HIP_MEMORY_SCOPE_AGENT) < tgt) {}
    (void)__hip_atomic_load(cnt, __ATOMIC_ACQUIRE, __HIP_MEMORY_SCOPE_AGENT);
  }
  __syncthreads();
}

// ---------------- generic 32x32 tiled transpose: dst[n*K+k] = src[k*N+n] ----------------
__global__ __launch_bounds__(256) void transpose_kernel(
    const float* __restrict__ src, float* __restrict__ dst, int K, int N)
{
  __shared__ float tile[32][33];
  const int tx = threadIdx.x & 31, ty = threadIdx.x >> 5;
  const int bn = blockIdx.x * 32, bk = blockIdx.y * 32;
  #pragma unroll
  for (int i = 0; i < 4; ++i)
    tile[ty + i * 8][tx] = src[(size_t)(bk + ty + i * 8) * N + bn + tx];
  __syncthreads();
  #pragma unroll
  for (int i = 0; i < 4; ++i)
    dst[(size_t)(bn + ty + i * 8) * K + bk + tx] = tile[tx][ty + i * 8];
}

// ---------------- Wh fp32 -> bf16 padded [512][NPAD] ----------------
__global__ __launch_bounds__(256) void convwh_kernel(
    const float* __restrict__ wh, u16* __restrict__ whb)
{
  const int k = blockIdx.y;
  const int v0 = (blockIdx.x * 256 + threadIdx.x) * 2;
  if (v0 >= NPAD) return;
  float a = (v0     < Vn) ? wh[(size_t)k * Vn + v0]     : 0.f;
  float b = (v0 + 1 < Vn) ? wh[(size_t)k * Vn + v0 + 1] : 0.f;
  u32 pack = (u32)f2bf(a) | ((u32)f2bf(b) << 16);
  *(u32*)&whb[(size_t)k * NPAD + v0] = pack;
}

// ---------------- persistent recurrence ----------------
__global__ __launch_bounds__(RNT, 1) void rec_kernel(
    const int* __restrict__ ids, const float* __restrict__ emb,
    const float* __restrict__ wtC1_0, const float* __restrict__ wtG1_0,
    const float* __restrict__ wtC2_0, const float* __restrict__ wtR_0,
    const float* __restrict__ wtC1_1, const float* __restrict__ wtG1_1,
    const float* __restrict__ wtC2_1, const float* __restrict__ wtR_1,
    const float* __restrict__ bc1_0, const float* __restrict__ bg1_0,
    const float* __restrict__ bc2_0, const float* __restrict__ br_0,
    const float* __restrict__ wg2_0, const float* __restrict__ bg2_0,
    const float* __restrict__ bc1_1, const float* __restrict__ bg1_1,
    const float* __restrict__ bc2_1, const float* __restrict__ br_1,
    const float* __restrict__ wg2_1, const float* __restrict__ bg2_1,
    float* __restrict__ hpre0, float* __restrict__ hpre1,
    float* __restrict__ pstats, float* __restrict__ cand1,
    float* __restrict__ g1buf, float* __restrict__ rbuf,
    u32* cnt, float* __restrict__ gates_out)
{
  __shared__ float xbuf[4 * 1536];
  __shared__ float h1m[4], h1i[4], h2m[4], h2i[4], inpm[4], inpi[4];
  __shared__ float savm[2][4], savi[2][4];
  __shared__ float gateL[4], candL[4][4];
  __shared__ int   ids4[4];

  const int tid = threadIdx.x, g = blockIdx.x;
  const int w = tid >> 6, lane = tid & 63;
  unsigned ep = 0;

  if (tid < 8) { savm[tid >> 2][tid & 3] = 0.f; savi[tid >> 2][tid & 3] = 0.f; }
  __syncthreads();

  for (int t = 0; t < Tn; ++t) {
    for (int l = 0; l < 2; ++l) {
      const int C = l ? 1536 : 1280;
      const int e = l ? 512 : 256;
      const float* wtC1 = l ? wtC1_1 : wtC1_0;
      const float* wtG1 = l ? wtG1_1 : wtG1_0;
      const float* wtC2 = l ? wtC2_1 : wtC2_0;
      const float* wtR  = l ? wtR_1  : wtR_0;
      const float* bc1  = l ? bc1_1 : bc1_0;
      const float* bg1  = l ? bg1_1 : bg1_0;
      const float* bc2  = l ? bc2_1 : bc2_0;
      const float* br   = l ? br_1  : br_0;
      const float* wg2  = l ? wg2_1 : wg2_0;
      const float* bg2  = l ? bg2_1 : bg2_0;
      float* hp = l ? hpre1 : hpre0;

      // ================= Phase A =================
      if (tid < 4) { h2m[tid] = savm[l][tid]; h2i[tid] = savi[l][tid]; }
      if (l == 0 && tid >= 64 && tid < 68) ids4[tid - 64] = ids[(tid - 64) * Tn + t];
      {
        // deterministic reduce of per-block LN partials
        int set = tid >> 7, b = (tid >> 5) & 3, i = tid & 31;
        int lsel = set ? 0 : l;
        float s = 0.f, ss = 0.f;
        #pragma unroll
        for (int m4 = 0; m4 < 4; ++m4) {
          const float* pp = pstats + ((size_t)(lsel * RG + (i + m4 * 32)) * 4 + b) * 2;
          s += pp[0]; ss += pp[1];
        }
        #pragma unroll
        for (int off = 16; off; off >>= 1) { s += __shfl_xor(s, off); ss += __shfl_xor(ss, off); }
        if (i == 0) {
          float m = s * (1.f / Hn);
          float var = ss * (1.f / Hn) - m * m;
          float inv = rsqrtf(var + 1e-5f);
          if (set == 0) { h1m[b] = m; h1i[b] = inv; }
          else          { inpm[b] = m; inpi[b] = inv; }
        }
      }
      __syncthreads();
      if (tid < 4) { savm[l][tid] = h1m[tid]; savi[l][tid] = h1i[tid]; }

      // stage ctx = [h1 | h2 | inp] (fp32, normalized on the fly)
      for (int b = 0; b < 4; ++b) {
        float* xr = xbuf + b * 1536;
        for (int k = tid; k < C; k += RNT) {
          float v;
          int sec = k >> 9;
          if (sec == 0) {
            v = 0.f;
            if (t >= 1) v = (hp[((size_t)(b * Tn + t - 1)) * Hn + k] - h1m[b]) * h1i[b];
          } else if (sec == 1) {
            v = 0.f;
            if (t >= 2) v = (hp[((size_t)(b * Tn + t - 2)) * Hn + (k - 512)] - h2m[b]) * h2i[b];
          } else {
            int kk = k - 1024;
            if (l == 0) v = emb[(size_t)ids4[b] * En + kk];
            else        v = (hpre0[((size_t)(b * Tn + t)) * Hn + kk] - inpm[b]) * inpi[b];
          }
          xr[k] = v;
        }
      }
      __syncthreads();

      // matvecs: wave0/1: Wc1 (4 cols each); wave2: Wg1; wave3: Wr
      {
        const float* wb; int K2, xo, jb, kind;
        if (w < 2)      { wb = wtC1; K2 = C; xo = 0;    jb = g * 8 + w * 4; kind = 0; }
        else if (w == 2){ wb = wtG1; K2 = C; xo = 0;    jb = g * 4;         kind = 1; }
        else            { wb = wtR;  K2 = e; xo = 1024; jb = g * 4;         kind = 2; }
        float acc[4][4];
        #pragma unroll
        for (int c = 0; c < 4; ++c)
          #pragma unroll
          for (int b = 0; b < 4; ++b) acc[c][b] = 0.f;
        for (int k = lane; k < K2; k += 64) {
          float x0 = xbuf[xo + k], x1 = xbuf[1536 + xo + k];
          float x2 = xbuf[3072 + xo + k], x3 = xbuf[4608 + xo + k];
          #pragma unroll
          for (int c = 0; c < 4; ++c) {
            float wv = wb[(size_t)(jb + c) * K2 + k];
            acc[c][0] = fmaf(wv, x0, acc[c][0]);
            acc[c][1] = fmaf(wv, x1, acc[c][1]);
            acc[c][2] = fmaf(wv, x2, acc[c][2]);
            acc[c][3] = fmaf(wv, x3, acc[c][3]);
          }
        }
        #pragma unroll
        for (int off = 32; off; off >>= 1)
          #pragma unroll
          for (int c = 0; c < 4; ++c)
            #pragma unroll
            for (int b = 0; b < 4; ++b)
              acc[c][b] += __shfl_xor(acc[c][b], off);
        if (lane == 0) {
          #pragma unroll
          for (int c = 0; c < 4; ++c) {
            int j = jb + c;
            if (kind == 0) {
              float bb = bc1[j];
              #pragma unroll
              for (int b = 0; b < 4; ++b) cand1[b * 1024 + j] = fmaxf(acc[c][b] + bb, 0.f);
            } else if (kind == 1) {
              float bb = bg1[j];
              #pragma unroll
              for (int b = 0; b < 4; ++b) g1buf[b * 512 + j] = tanhf(acc[c][b] + bb);
            } else {
              float bb = br[j];
              #pragma unroll
              for (int b = 0; b < 4; ++b) rbuf[b * 512 + j] = acc[c][b] + bb;
            }
          }
        }
      }
      gbar(cnt, ep);

      // ================= Phase B =================
      for (int idx = tid; idx < 4096; idx += RNT)
        xbuf[(idx >> 10) * 1536 + (idx & 1023)] = cand1[idx];
      for (int idx = tid; idx < 2048; idx += RNT)
        xbuf[(idx >> 9) * 1536 + 1024 + (idx & 511)] = g1buf[idx];
      __syncthreads();
      {
        int j = g * 4 + w;
        float acc[4] = {0.f, 0.f, 0.f, 0.f};
        for (int k = lane; k < 1024; k += 64) {
          float wv = wtC2[(size_t)j * 1024 + k];
          acc[0] = fmaf(wv, xbuf[k],        acc[0]);
          acc[1] = fmaf(wv, xbuf[1536 + k], acc[1]);
          acc[2] = fmaf(wv, xbuf[3072 + k], acc[2]);
          acc[3] = fmaf(wv, xbuf[4608 + k], acc[3]);
        }
        #pragma unroll
        for (int off = 32; off; off >>= 1)
          #pragma unroll
          for (int b = 0; b < 4; ++b) acc[b] += __shfl_xor(acc[b], off);
        // gate for batch w
        float p = 0.f;
        for (int k = lane; k < 512; k += 64) p += xbuf[w * 1536 + 1024 + k] * wg2[k];
        #pragma unroll
        for (int off = 32; off; off >>= 1) p += __shfl_xor(p, off);
        if (lane == 0) {
          float bb = bc2[j];
          #pragma unroll
          for (int b = 0; b < 4; ++b) candL[w][b] = acc[b] + bb;
          gateL[w] = 1.f / (1.f + expf(-(p + bg2[0])));
        }
      }
      __syncthreads();
      if (l == 1 && g == 0 && tid < 4) gates_out[tid * Tn + t] = gateL[tid];
      if (tid < 16) {
        int c = tid >> 2, b = tid & 3, j = g * 4 + c;
        float h1v = 0.f;
        if (t >= 1) h1v = (hp[((size_t)(b * Tn + t - 1)) * Hn + j] - h1m[b]) * h1i[b];
        float hv = h1v + gateL[b] * candL[c][b] + 0.1f * rbuf[b * 512 + j];
        hp[((size_t)(b * Tn + t)) * Hn + j] = hv;
        float s = hv, ss = hv * hv;
        s += __shfl_xor(s, 4); ss += __shfl_xor(ss, 4);
        s += __shfl_xor(s, 8); ss += __shfl_xor(ss, 8);
        if (c == 0) {
          float* pp = pstats + ((size_t)(l * RG + g) * 4 + b) * 2;
          pp[0] = s; pp[1] = ss;
        }
      }
      gbar(cnt, ep);
    }
  }
}

// ---------------- attention scores (+ hist = LN(hpre1)) ----------------
__global__ __launch_bounds__(256) void scores_kernel(
    const float* __restrict__ hpre1,
    const float* __restrict__ wa1, const float* __restrict__ ba1,
    const float* __restrict__ wa2, const float* __restrict__ ba2,
    float* __restrict__ hist, float* __restrict__ scores)
{
  __shared__ float xs[8][512];
  __shared__ float mm[8], ii[8];
  __shared__ float wacc[4][8];
  const int tid = threadIdx.x, bid = blockIdx.x;

  for (int idx = tid; idx < 4096; idx += 256)
    xs[idx >> 9][idx & 511] = hpre1[(size_t)(bid * 8) * Hn + idx];
  __syncthreads();
  {
    int r = tid >> 5, i = tid & 31;
    float s = 0.f, ss = 0.f;
    for (int k = i; k < 512; k += 32) { float v = xs[r][k]; s += v; ss += v * v; }
    #pragma unroll
    for (int off = 16; off; off >>= 1) { s += __shfl_xor(s, off); ss += __shfl_xor(ss, off); }
    if (i == 0) {
      float m = s * (1.f / Hn);
      float var = ss * (1.f / Hn) - m * m;
      mm[r] = m; ii[r] = rsqrtf(var + 1e-5f);
    }
  }
  __syncthreads();
  for (int idx = tid; idx < 4096; idx += 256) {
    int r = idx >> 9, k = idx & 511;
    float x = (xs[r][k] - mm[r]) * ii[r];
    xs[r][k] = x;
    hist[(size_t)(bid * 8) * Hn + idx] = x;
  }
  __syncthreads();

  float pr[8] = {0.f, 0.f, 0.f, 0.f, 0.f, 0.f, 0.f, 0.f};
  #pragma unroll
  for (int cc = 0; cc < 2; ++cc) {
    int c = tid + cc * 256;
    float a[8] = {0.f, 0.f, 0.f, 0.f, 0.f, 0.f, 0.f, 0.f};
    for (int k = 0; k < 512; ++k) {
      float wv = wa1[(size_t)k * 512 + c];
      #pragma unroll
      for (int r = 0; r < 8; ++r) a[r] = fmaf(xs[r][k], wv, a[r]);
    }
    float b1 = ba1[c], w2 = wa2[c];
    #pragma unroll
    for (int r = 0; r < 8; ++r) pr[r] += tanhf(a[r] + b1) * w2;
  }
  int lane = tid & 63, wq = tid >> 6;
  #pragma unroll
  for (int off = 32; off; off >>= 1)
    #pragma unroll
    for (int r = 0; r < 8; ++r) pr[r] += __shfl_xor(pr[r], off);
  if (lane == 0) {
    #pragma unroll
    for (int r = 0; r < 8; ++r) wacc[wq][r] = pr[r];
  }
  __syncthreads();
  if (tid < 8)
    scores[bid * 8 + tid] = wacc[0][tid] + wacc[1][tid] + wacc[2][tid] + wacc[3][tid] + ba2[0];
}

// ---------------- prefix-softmax cumsum -> attended (bf16) ----------------
__global__ __launch_bounds__(256) void cumsum_kernel(
    const float* __restrict__ scores, const float* __restrict__ hist,
    u16* __restrict__ att)
{
  __shared__ float ee[512], den[512], sb[512], red[256];
  const int tid = threadIdx.x, b = blockIdx.x;
  float s0 = scores[b * Tn + tid], s1 = scores[b * Tn + tid + 256];
  red[tid] = fmaxf(s0, s1);
  __syncthreads();
  for (int s = 128; s; s >>= 1) { if (tid < s) red[tid] = fmaxf(red[tid], red[tid + s]); __syncthreads(); }
  float m = red[0];
  ee[tid] = expf(s0 - m); ee[tid + 256] = expf(s1 - m);
  den[tid] = ee[tid]; den[tid + 256] = ee[tid + 256];
  __syncthreads();
  float* A = den; float* D = sb;
  for (int off = 1; off < 512; off <<= 1) {
    for (int t2 = tid; t2 < 512; t2 += 256) { float v = A[t2]; if (t2 >= off) v += A[t2 - off]; D[t2] = v; }
    __syncthreads();
    float* tmp = A; A = D; D = tmp;
  }
  float* R = D;
  for (int t2 = tid; t2 < 512; t2 += 256) R[t2] = 1.f / A[t2];
  __syncthreads();

  const int h0 = tid * 2;
  float ax = 0.f, ay = 0.f;
  for (int t = 0; t < 512; ++t) {
    const float* hpp = hist + ((size_t)(b * Tn + t)) * Hn + h0;
    float x0 = hpp[0], x1 = hpp[1];
    float et = ee[t], rd = R[t];
    ax = fmaf(et, x0, ax); ay = fmaf(et, x1, ay);
    u32 pack = (u32)f2bf(x0 + ax * rd) | ((u32)f2bf(x1 + ay * rd) << 16);
    *(u32*)(att + ((size_t)(b * Tn + t)) * Hn + h0) = pack;
  }
}

// ---------------- final GEMM: att[2048x512]bf16 @ WhB[512xNPAD]bf16 + bh -> fp32 ----------------
typedef short bf16x8_t __attribute__((ext_vector_type(8)));
typedef float f32x4_t  __attribute__((ext_vector_type(4)));

__global__ __launch_bounds__(256) void gemm_kernel(
    const u16* __restrict__ Aw, const u16* __restrict__ Bw,
    const float* __restrict__ bh, float* __restrict__ out)
{
  __shared__ u16 Alds[128 * 64];   // XOR-swizzled
  __shared__ u16 Blds[64 * 128];   // linear [k][n]
  const int tid = threadIdx.x;
  const int n0 = blockIdx.x * 128, m0 = blockIdx.y * 128;
  const int w = tid >> 6, lane = tid & 63;
  const int wm = (w & 1) * 64, wn = (w >> 1) * 64;

  f32x4_t acc[4][4];
  #pragma unroll
  for (int i = 0; i < 4; ++i)
    #pragma unroll
    for (int j = 0; j < 4; ++j) acc[i][j] = (f32x4_t){0.f, 0.f, 0.f, 0.f};

  for (int kt = 0; kt < 8; ++kt) {
    const int k0 = kt * 64;
    {
      int row = tid >> 1, kc = (tid & 1) * 32;
      #pragma unroll
      for (int jj = 0; jj < 4; ++jj) {
        uint4 v = *(const uint4*)(Aw + (size_t)(m0 + row) * 512 + k0 + kc + jj * 8);
        int byte = row * 128 + (kc + jj * 8) * 2;
        byte ^= (row & 7) << 4;
        *(uint4*)((char*)Alds + byte) = v;
      }
    }
    {
      #pragma unroll
      for (int q = 0; q < 4; ++q) {
        int r = (tid >> 4) + q * 16, c8 = (tid & 15) * 8;
        uint4 v = *(const uint4*)(Bw + (size_t)(k0 + r) * NPAD + n0 + c8);
        *(uint4*)&Blds[r * 128 + c8] = v;
      }
    }
    __syncthreads();
    #pragma unroll
    for (int kh = 0; kh < 2; ++kh) {
      bf16x8_t af[4];
      #pragma unroll
      for (int i = 0; i < 4; ++i) {
        int row = wm + i * 16 + (lane & 15);
        int byte = row * 128 + kh * 64 + (lane >> 4) * 16;
        byte ^= (row & 7) << 4;
        af[i] = *(const bf16x8_t*)((const char*)Alds + byte);
      }
      const int kb = kh * 32 + (lane >> 4) * 8;
      #pragma unroll
      for (int j = 0; j < 4; ++j) {
        int col = wn + j * 16 + (lane & 15);
        bf16x8_t bf;
        #pragma unroll
        for (int jj = 0; jj < 8; ++jj) bf[jj] = (short)Blds[(kb + jj) * 128 + col];
        #pragma unroll
        for (int i = 0; i < 4; ++i)
          acc[i][j] = __builtin_amdgcn_mfma_f32_16x16x32_bf16(af[i], bf, acc[i][j], 0, 0, 0);
      }
    }
    __syncthreads();
  }
  #pragma unroll
  for (int j = 0; j < 4; ++j) {
    int col = n0 + wn + j * 16 + (lane & 15);
    if (col < Vn) {
      float bias = bh[col];
      #pragma unroll
      for (int i = 0; i < 4; ++i) {
        int rbase = m0 + wm + i * 16 + (lane >> 4) * 4;
        #pragma unroll
        for (int r = 0; r < 4; ++r)
          out[(size_t)(rbase + r) * Vn + col] = acc[i][j][r] + bias;
      }
    }
  }
}

// ---------------- host ----------------
extern "C" void kernel_launch(void* const* d_in, const int* in_sizes, int n_in,
                              void* d_out, int out_size, void* d_ws, size_t ws_size,
                              hipStream_t stream) {
  const int*   ids  = (const int*)d_in[0];
  const float* emb  = (const float*)d_in[1];
  const float* Wc1_0 = (const float*)d_in[2];  const float* bc1_0 = (const float*)d_in[3];
  const float* Wc2_0 = (const float*)d_in[4];  const float* bc2_0 = (const float*)d_in[5];
  const float* Wg1_0 = (const float*)d_in[6];  const float* bg1_0 = (const float*)d_in[7];
  const float* Wg2_0 = (const float*)d_in[8];  const float* bg2_0 = (const float*)d_in[9];
  const float* Wr_0  = (const float*)d_in[10]; const float* br_0  = (const float*)d_in[11];
  const float* Wc1_1 = (const float*)d_in[12]; const float* bc1_1 = (const float*)d_in[13];
  const float* Wc2_1 = (const float*)d_in[14]; const float* bc2_1 = (const float*)d_in[15];
  const float* Wg1_1 = (const float*)d_in[16]; const float* bg1_1 = (const float*)d_in[17];
  const float* Wg2_1 = (const float*)d_in[18]; const float* bg2_1 = (const float*)d_in[19];
  const float* Wr_1  = (const float*)d_in[20]; const float* br_1  = (const float*)d_in[21];
  const float* Wa1 = (const float*)d_in[22]; const float* ba1 = (const float*)d_in[23];
  const float* Wa2 = (const float*)d_in[24]; const float* ba2 = (const float*)d_in[25];
  const float* Wh  = (const float*)d_in[26]; const float* bh  = (const float*)d_in[27];

  float* out = (float*)d_out;
  char*  ws  = (char*)d_ws;

  const size_t OFF_CNT  = 0;
  const size_t OFF_PST  = 1024;
  const size_t OFF_WT   = 16384;                       // 23,068,672 B
  const size_t OFF_HP0  = OFF_WT  + 23068672;          // 4 MB
  const size_t OFF_HP1  = OFF_HP0 + 4194304;           // 4 MB
  const size_t OFF_CAND = OFF_HP1 + 4194304;           // 16 KB
  const size_t OFF_G1   = OFF_CAND + 16384;            // 8 KB
  const size_t OFF_R    = OFF_G1  + 8192;              // 8 KB
  const size_t OFF_HIST = OFF_R   + 8192;              // 4 MB
  const size_t OFF_SCO  = OFF_HIST + 4194304;          // 8 KB
  const size_t OFF_ATT  = OFF_SCO + 8192;              // 2 MB
  const size_t OFF_WHB  = OFF_ATT + 2097152;           // 51.5 MB

  u32*   cnt    = (u32*)(ws + OFF_CNT);
  float* pstats = (float*)(ws + OFF_PST);
  float* wt     = (float*)(ws + OFF_WT);
  float* hpre0  = (float*)(ws + OFF_HP0);
  float* hpre1  = (float*)(ws + OFF_HP1);
  float* cand1  = (float*)(ws + OFF_CAND);
  float* g1buf  = (float*)(ws + OFF_G1);
  float* rbuf   = (float*)(ws + OFF_R);
  float* hist   = (float*)(ws + OFF_HIST);
  float* scores = (float*)(ws + OFF_SCO);
  u16*   att    = (u16*)(ws + OFF_ATT);
  u16*   whb    = (u16*)(ws + OFF_WHB);
  float* gates  = out + (size_t)Bn * Tn * Vn;

  // transposed weight sub-buffers (element offsets)
  float* wtC1_0 = wt;
  float* wtG1_0 = wt + 1310720;
  float* wtC2_0 = wt + 1966080;
  float* wtR_0  = wt + 2490368;
  float* wtC1_1 = wt + 2621440;
  float* wtG1_1 = wt + 4194304;
  float* wtC2_1 = wt + 4980736;
  float* wtR_1  = wt + 5505024;

  hipMemsetAsync(ws, 0, 16384, stream);   // cnt + pstats

  transpose_kernel<<<dim3(32, 40), 256, 0, stream>>>(Wc1_0, wtC1_0, 1280, 1024);
  transpose_kernel<<<dim3(16, 40), 256, 0, stream>>>(Wg1_0, wtG1_0, 1280, 512);
  transpose_kernel<<<dim3(16, 32), 256, 0, stream>>>(Wc2_0, wtC2_0, 1024, 512);
  transpose_kernel<<<dim3(16,  8), 256, 0, stream>>>(Wr_0,  wtR_0,   256, 512);
  transpose_kernel<<<dim3(32, 48), 256, 0, stream>>>(Wc1_1, wtC1_1, 1536, 1024);
  transpose_kernel<<<dim3(16, 48), 256, 0, stream>>>(Wg1_1, wtG1_1, 1536, 512);
  transpose_kernel<<<dim3(16, 32), 256, 0, stream>>>(Wc2_1, wtC2_1, 1024, 512);
  transpose_kernel<<<dim3(16, 16), 256, 0, stream>>>(Wr_1,  wtR_1,   512, 512);

  convwh_kernel<<<dim3(99, 512), 256, 0, stream>>>(Wh, whb);

  rec_kernel<<<dim3(RG), dim3(RNT), 0, stream>>>(
      ids, emb,
      wtC1_0, wtG1_0, wtC2_0, wtR_0, wtC1_1, wtG1_1, wtC2_1, wtR_1,
      bc1_0, bg1_0, bc2_0, br_0, Wg2_0, bg2_0,
      bc1_1, bg1_1, bc2_1, br_1, Wg2_1, bg2_1,
      hpre0, hpre1, pstats, cand1, g1buf, rbuf, cnt, gates);

  scores_kernel<<<dim3(256), 256, 0, stream>>>(hpre1, Wa1, ba1, Wa2, ba2, hist, scores);

  cumsum_kernel<<<dim3(Bn), 256, 0, stream>>>(scores, hist, att);

  gemm_kernel<<<dim3(393, 16), 256, 0, stream>>>(att, whb, bh, out);
}

// Round 3
// 24753.568 us; speedup vs baseline: 1.6363x; 1.6363x over previous
//
#include <hip/hip_runtime.h>
#include <hip/hip_fp16.h>
#include <cstdint>
#include <cstddef>

typedef unsigned short u16;
typedef unsigned int   u32;

#define Bn 4
#define Tn 512
#define Hn 512
#define En 256
#define Vn 50257
#define NPAD 50304

#define RG  128
#define RNT 256

// ---- LDS byte offsets (dynamic smem) ----
// fp16 weight slices (halfs): L0: C1@0(10240) G1@10240(5120) R@15360(1024) C2@16384(4096)
//                             L1: C1@20480(12288) G1@32768(6144) R@38912(2048) C2@40960(4096)
#define XB0_B  90112
#define XB1_B  114688
#define WG2_B  139264
#define BC1_B  143360
#define BG1_B  143424
#define BR_B   143456
#define BC2_B  143488
#define BG2_B  143520
#define MI_B   143528
#define GL_B   143592
#define CL_B   143608
#define RL_B   143672
#define IDS_B  143736
#define REC_LDS 143808

__device__ __forceinline__ u16 f2bf(float f) {
  u32 x; __builtin_memcpy(&x, &f, 4);
  u32 r = (x + 0x7fffu + ((x >> 16) & 1u)) >> 16;
  return (u16)r;
}

__device__ __forceinline__ float gld(const float* p) {
  return __hip_atomic_load(p, __ATOMIC_RELAXED, __HIP_MEMORY_SCOPE_AGENT);
}
__device__ __forceinline__ void gst(float* p, float v) {
  __hip_atomic_store(p, v, __ATOMIC_RELAXED, __HIP_MEMORY_SCOPE_AGENT);
}

// flag-broadcast grid barrier: own-slot store + all-poll (no RMW contention, no acquire-invalidate)
__device__ __forceinline__ void gbar(u32* flags, unsigned& ep, int g) {
  ++ep;
  __builtin_amdgcn_fence(__ATOMIC_RELEASE, "agent");
  __syncthreads();                       // drains all threads' stores (vmcnt0 before s_barrier)
  if (threadIdx.x == 0)
    __hip_atomic_store(&flags[g * 32], ep, __ATOMIC_RELAXED, __HIP_MEMORY_SCOPE_AGENT);
  if (threadIdx.x < 64) {
    bool wait;
    do {
      u32 a = __hip_atomic_load(&flags[threadIdx.x * 32], __ATOMIC_RELAXED, __HIP_MEMORY_SCOPE_AGENT);
      u32 b = __hip_atomic_load(&flags[(threadIdx.x + 64) * 32], __ATOMIC_RELAXED, __HIP_MEMORY_SCOPE_AGENT);
      wait = (a < ep) || (b < ep);
    } while (__any(wait));
  }
  __syncthreads();
}

// ---------------- transpose + fp32->fp16: dst[n*K+k] = (half)src[k*N+n] ----------------
__global__ __launch_bounds__(256) void transpose_h(
    const float* __restrict__ src, __half* __restrict__ dst, int K, int N)
{
  __shared__ float tile[32][33];
  const int tx = threadIdx.x & 31, ty = threadIdx.x >> 5;
  const int bn = blockIdx.x * 32, bk = blockIdx.y * 32;
  #pragma unroll
  for (int i = 0; i < 4; ++i)
    tile[ty + i * 8][tx] = src[(size_t)(bk + ty + i * 8) * N + bn + tx];
  __syncthreads();
  #pragma unroll
  for (int i = 0; i < 4; ++i)
    dst[(size_t)(bn + ty + i * 8) * K + bk + tx] = __float2half(tile[tx][ty + i * 8]);
}

// ---------------- Wh fp32 -> bf16 padded [512][NPAD] ----------------
__global__ __launch_bounds__(256) void convwh_kernel(
    const float* __restrict__ wh, u16* __restrict__ whb)
{
  const int k = blockIdx.y;
  const int v0 = (blockIdx.x * 256 + threadIdx.x) * 2;
  if (v0 >= NPAD) return;
  float a = (v0     < Vn) ? wh[(size_t)k * Vn + v0]     : 0.f;
  float b = (v0 + 1 < Vn) ? wh[(size_t)k * Vn + v0 + 1] : 0.f;
  u32 pack = (u32)f2bf(a) | ((u32)f2bf(b) << 16);
  *(u32*)&whb[(size_t)k * NPAD + v0] = pack;
}

// ---------------- persistent recurrence (weights LDS-resident fp16) ----------------
__global__ __launch_bounds__(RNT, 1) void rec_kernel(
    const int* __restrict__ ids, const float* __restrict__ emb,
    const u16* __restrict__ wtC1_0, const u16* __restrict__ wtG1_0,
    const u16* __restrict__ wtC2_0, const u16* __restrict__ wtR_0,
    const u16* __restrict__ wtC1_1, const u16* __restrict__ wtG1_1,
    const u16* __restrict__ wtC2_1, const u16* __restrict__ wtR_1,
    const float* __restrict__ bc1_0, const float* __restrict__ bg1_0,
    const float* __restrict__ bc2_0, const float* __restrict__ br_0,
    const float* __restrict__ wg2_0, const float* __restrict__ bg2_0,
    const float* __restrict__ bc1_1, const float* __restrict__ bg1_1,
    const float* __restrict__ bc2_1, const float* __restrict__ br_1,
    const float* __restrict__ wg2_1, const float* __restrict__ bg2_1,
    float* __restrict__ hq0, float* __restrict__ hq1,
    float* __restrict__ pstats, float* __restrict__ cand1, float* __restrict__ g1buf,
    u32* flags, float* __restrict__ histR, float* __restrict__ gates_out)
{
  extern __shared__ char smem[];
  u16*   WL    = (u16*)smem;
  float* xb0   = (float*)(smem + XB0_B);
  float* xb1   = (float*)(smem + XB1_B);
  float* wg2L  = (float*)(smem + WG2_B);
  float* bc1L  = (float*)(smem + BC1_B);
  float* bg1L  = (float*)(smem + BG1_B);
  float* brL   = (float*)(smem + BR_B);
  float* bc2L  = (float*)(smem + BC2_B);
  float* bg2L  = (float*)(smem + BG2_B);
  float* mi    = (float*)(smem + MI_B);     // [0..3]=h1m [4..7]=h1i [8..11]=inpm [12..15]=inpi
  float* gateL = (float*)(smem + GL_B);
  float* candL = (float*)(smem + CL_B);     // [c][b]
  float* rloc  = (float*)(smem + RL_B);     // [c][b]
  int*   ids4  = (int*)(smem + IDS_B);

  const int tid = threadIdx.x, g = blockIdx.x;
  const int w = tid >> 6, lane = tid & 63;
  unsigned ep = 0;

  // ---- one-time staging ----
  auto cpw = [&](const u16* srcT, int K, int nc, int j0, int off_h) {
    const u32* s32 = (const u32*)(srcT + (size_t)j0 * K);
    u32* d32 = (u32*)(WL + off_h);
    int n = (nc * K) >> 1;
    for (int p = tid; p < n; p += RNT) d32[p] = s32[p];
  };
  cpw(wtC1_0, 1280, 8, g * 8, 0);
  cpw(wtG1_0, 1280, 4, g * 4, 10240);
  cpw(wtR_0,   256, 4, g * 4, 15360);
  cpw(wtC2_0, 1024, 4, g * 4, 16384);
  cpw(wtC1_1, 1536, 8, g * 8, 20480);
  cpw(wtG1_1, 1536, 4, g * 4, 32768);
  cpw(wtR_1,   512, 4, g * 4, 38912);
  cpw(wtC2_1, 1024, 4, g * 4, 40960);
  for (int k = tid; k < 512; k += RNT) { wg2L[k] = wg2_0[k]; wg2L[512 + k] = wg2_1[k]; }
  if (tid < 8)       { bc1L[tid] = bc1_0[g * 8 + tid]; bc1L[8 + tid] = bc1_1[g * 8 + tid]; }
  else if (tid < 12) {
    int c = tid - 8;
    bg1L[c] = bg1_0[g * 4 + c]; bg1L[4 + c] = bg1_1[g * 4 + c];
    brL[c]  = br_0[g * 4 + c];  brL[4 + c]  = br_1[g * 4 + c];
    bc2L[c] = bc2_0[g * 4 + c]; bc2L[4 + c] = bc2_1[g * 4 + c];
  } else if (tid == 12) { bg2L[0] = bg2_0[0]; bg2L[1] = bg2_1[0]; }
  for (int idx = tid; idx < 12288; idx += RNT) xb0[idx] = 0.f;   // covers xb0+xb1
  __syncthreads();

  for (int t = 0; t < Tn; ++t) {
    for (int l = 0; l < 2; ++l) {
      const int C   = l ? 1536 : 1280;
      const int e   = l ? 512 : 256;
      const int oC1 = l ? 20480 : 0;
      const int oG1 = l ? 32768 : 10240;
      const int oR  = l ? 38912 : 15360;
      const int oC2 = l ? 40960 : 16384;
      float* xbl = l ? xb1 : xb0;
      float* hq  = l ? hq1 : hq0;

      // ======== Phase A ========
      {
        int set = tid >> 7, b = (tid >> 5) & 3, i = tid & 31;
        int lsel = set ? 0 : l;
        float s = 0.f, ss = 0.f;
        #pragma unroll
        for (int m4 = 0; m4 < 4; ++m4) {
          const float* pp = pstats + (((size_t)lsel * RG + i + m4 * 32) << 3) + b * 2;
          s += gld(pp); ss += gld(pp + 1);
        }
        #pragma unroll
        for (int off = 16; off; off >>= 1) { s += __shfl_xor(s, off); ss += __shfl_xor(ss, off); }
        if (i == 0) {
          float m = s * (1.f / 512.f);
          float var = ss * (1.f / 512.f) - m * m;
          mi[set * 8 + b] = m; mi[set * 8 + 4 + b] = rsqrtf(var + 1e-5f);
        }
      }
      if (l == 0 && tid >= 192 && tid < 196) ids4[tid - 192] = ids[(tid - 192) * Tn + t];
      __syncthreads();

      // stage: h2 <- old h1 (LDS copy); h1 <- LN(hq); inp <- emb / LN(hq0)
      for (int idx = tid; idx < 2048; idx += RNT) {
        int b = idx >> 9, k = idx & 511;
        float* row = xbl + b * 1536;
        float old = row[k];
        float nh = 0.f;
        if (t >= 1) nh = (gld(hq + b * 512 + k) - mi[b]) * mi[4 + b];
        row[512 + k] = old;
        row[k] = nh;
      }
      if (l == 0) {
        for (int idx = tid; idx < 1024; idx += RNT) {
          int b = idx >> 8, k = idx & 255;
          xbl[b * 1536 + 1024 + k] = emb[(size_t)ids4[b] * En + k];
        }
      } else {
        for (int idx = tid; idx < 2048; idx += RNT) {
          int b = idx >> 9, k = idx & 511;
          xbl[b * 1536 + 1024 + k] = (gld(hq0 + b * 512 + k) - mi[8 + b]) * mi[12 + b];
        }
      }
      __syncthreads();

      // matvecs from LDS: wave0/1: Wc1 (4 cols each); wave2: Wg1; wave3: Wr
      {
        const u16* wbase; int Kp, xo;
        if (w < 2)      { wbase = WL + oC1 + w * 4 * C; Kp = C >> 1; xo = 0; }
        else if (w == 2){ wbase = WL + oG1;             Kp = C >> 1; xo = 0; }
        else            { wbase = WL + oR;              Kp = e >> 1; xo = 1024; }
        const int K2 = Kp * 2;
        float acc[4][4];
        #pragma unroll
        for (int c = 0; c < 4; ++c)
          #pragma unroll
          for (int b = 0; b < 4; ++b) acc[c][b] = 0.f;
        for (int p = lane; p < Kp; p += 64) {
          float2 xv[4];
          #pragma unroll
          for (int b = 0; b < 4; ++b)
            xv[b] = *(const float2*)(xbl + b * 1536 + xo + 2 * p);
          #pragma unroll
          for (int c = 0; c < 4; ++c) {
            __half2 hw = *(const __half2*)(wbase + c * K2 + 2 * p);
            float2 wf = __half22float2(hw);
            #pragma unroll
            for (int b = 0; b < 4; ++b)
              acc[c][b] = fmaf(wf.x, xv[b].x, fmaf(wf.y, xv[b].y, acc[c][b]));
          }
        }
        #pragma unroll
        for (int off = 32; off; off >>= 1)
          #pragma unroll
          for (int c = 0; c < 4; ++c)
            #pragma unroll
            for (int b = 0; b < 4; ++b) acc[c][b] += __shfl_xor(acc[c][b], off);
        if (lane == 0) {
          if (w < 2) {
            #pragma unroll
            for (int c = 0; c < 4; ++c) {
              int cc = w * 4 + c, j = g * 8 + cc;
              float bb = bc1L[l * 8 + cc];
              #pragma unroll
              for (int b = 0; b < 4; ++b) gst(cand1 + b * 1024 + j, fmaxf(acc[c][b] + bb, 0.f));
            }
          } else if (w == 2) {
            #pragma unroll
            for (int c = 0; c < 4; ++c) {
              int j = g * 4 + c;
              float bb = bg1L[l * 4 + c];
              #pragma unroll
              for (int b = 0; b < 4; ++b) gst(g1buf + b * 512 + j, tanhf(acc[c][b] + bb));
            }
          } else {
            #pragma unroll
            for (int c = 0; c < 4; ++c) {
              float bb = brL[l * 4 + c];
              #pragma unroll
              for (int b = 0; b < 4; ++b) rloc[c * 4 + b] = acc[c][b] + bb;
            }
          }
        }
      }
      gbar(flags, ep, g);

      // ======== Phase B ========
      for (int idx = tid; idx < 4096; idx += RNT) {
        int b = idx >> 10, k = idx & 1023;
        xbl[b * 1536 + 512 + k] = gld(cand1 + idx);
      }
      __syncthreads();
      {
        float p = 0.f;
        for (int k = lane; k < 512; k += 64) p += gld(g1buf + w * 512 + k) * wg2L[l * 512 + k];
        #pragma unroll
        for (int off = 32; off; off >>= 1) p += __shfl_xor(p, off);
        float acc[4] = {0.f, 0.f, 0.f, 0.f};
        const u16* wcol = WL + oC2 + w * 1024;
        for (int pr = lane; pr < 512; pr += 64) {
          __half2 hw = *(const __half2*)(wcol + 2 * pr);
          float2 wf = __half22float2(hw);
          #pragma unroll
          for (int b = 0; b < 4; ++b) {
            float2 xv = *(const float2*)(xbl + b * 1536 + 512 + 2 * pr);
            acc[b] = fmaf(wf.x, xv.x, fmaf(wf.y, xv.y, acc[b]));
          }
        }
        #pragma unroll
        for (int off = 32; off; off >>= 1)
          #pragma unroll
          for (int b = 0; b < 4; ++b) acc[b] += __shfl_xor(acc[b], off);
        if (lane == 0) {
          #pragma unroll
          for (int b = 0; b < 4; ++b) candL[w * 4 + b] = acc[b] + bc2L[l * 4 + w];
          gateL[w] = 1.f / (1.f + expf(-(p + bg2L[l])));
        }
      }
      __syncthreads();
      if (l == 1 && g == 0 && tid < 4) gates_out[tid * Tn + t] = gateL[tid];
      if (tid < 16) {
        int c = tid >> 2, b = tid & 3, j = g * 4 + c;
        float hv = xbl[b * 1536 + j] + gateL[b] * candL[c * 4 + b] + 0.1f * rloc[c * 4 + b];
        gst(hq + b * 512 + j, hv);
        if (l == 1) gst(histR + ((size_t)(b * Tn + t)) * Hn + j, hv);
        float s = hv, ss = hv * hv;
        s += __shfl_xor(s, 4); ss += __shfl_xor(ss, 4);
        s += __shfl_xor(s, 8); ss += __shfl_xor(ss, 8);
        if (c == 0) {
          float* pp = pstats + (((size_t)l * RG + g) << 3) + b * 2;
          gst(pp, s); gst(pp + 1, ss);
        }
      }
      gbar(flags, ep, g);
    }
  }
}

// ---------------- attention scores (+ histN = LN(histR)) ----------------
__global__ __launch_bounds__(256) void scores_kernel(
    const float* __restrict__ histR,
    const float* __restrict__ wa1, const float* __restrict__ ba1,
    const float* __restrict__ wa2, const float* __restrict__ ba2,
    float* __restrict__ histN, float* __restrict__ scores)
{
  __shared__ float xs[8][512];
  __shared__ float mm[8], ii[8];
  __shared__ float wacc[4][8];
  const int tid = threadIdx.x, bid = blockIdx.x;

  for (int idx = tid; idx < 4096; idx += 256)
    xs[idx >> 9][idx & 511] = histR[(size_t)(bid * 8) * Hn + idx];
  __syncthreads();
  {
    int r = tid >> 5, i = tid & 31;
    float s = 0.f, ss = 0.f;
    for (int k = i; k < 512; k += 32) { float v = xs[r][k]; s += v; ss += v * v; }
    #pragma unroll
    for (int off = 16; off; off >>= 1) { s += __shfl_xor(s, off); ss += __shfl_xor(ss, off); }
    if (i == 0) {
      float m = s * (1.f / Hn);
      float var = ss * (1.f / Hn) - m * m;
      mm[r] = m; ii[r] = rsqrtf(var + 1e-5f);
    }
  }
  __syncthreads();
  for (int idx = tid; idx < 4096; idx += 256) {
    int r = idx >> 9, k = idx & 511;
    float x = (xs[r][k] - mm[r]) * ii[r];
    xs[r][k] = x;
    histN[(size_t)(bid * 8) * Hn + idx] = x;
  }
  __syncthreads();

  float pr[8] = {0.f, 0.f, 0.f, 0.f, 0.f, 0.f, 0.f, 0.f};
  #pragma unroll
  for (int cc = 0; cc < 2; ++cc) {
    int c = tid + cc * 256;
    float a[8] = {0.f, 0.f, 0.f, 0.f, 0.f, 0.f, 0.f, 0.f};
    for (int k = 0; k < 512; ++k) {
      float wv = wa1[(size_t)k * 512 + c];
      #pragma unroll
      for (int r = 0; r < 8; ++r) a[r] = fmaf(xs[r][k], wv, a[r]);
    }
    float b1 = ba1[c], w2 = wa2[c];
    #pragma unroll
    for (int r = 0; r < 8; ++r) pr[r] += tanhf(a[r] + b1) * w2;
  }
  int lane = tid & 63, wq = tid >> 6;
  #pragma unroll
  for (int off = 32; off; off >>= 1)
    #pragma unroll
    for (int r = 0; r < 8; ++r) pr[r] += __shfl_xor(pr[r], off);
  if (lane == 0) {
    #pragma unroll
    for (int r = 0; r < 8; ++r) wacc[wq][r] = pr[r];
  }
  __syncthreads();
  if (tid < 8)
    scores[bid * 8 + tid] = wacc[0][tid] + wacc[1][tid] + wacc[2][tid] + wacc[3][tid] + ba2[0];
}

// ---------------- prefix-softmax cumsum -> attended (bf16) ----------------
__global__ __launch_bounds__(256) void cumsum_kernel(
    const float* __restrict__ scores, const float* __restrict__ histN,
    u16* __restrict__ att)
{
  __shared__ float ee[512], den[512], sb[512], red[256];
  const int tid = threadIdx.x, b = blockIdx.x;
  float s0 = scores[b * Tn + tid], s1 = scores[b * Tn + tid + 256];
  red[tid] = fmaxf(s0, s1);
  __syncthreads();
  for (int s = 128; s; s >>= 1) { if (tid < s) red[tid] = fmaxf(red[tid], red[tid + s]); __syncthreads(); }
  float m = red[0];
  ee[tid] = expf(s0 - m); ee[tid + 256] = expf(s1 - m);
  den[tid] = ee[tid]; den[tid + 256] = ee[tid + 256];
  __syncthreads();
  float* A = den; float* D = sb;
  for (int off = 1; off < 512; off <<= 1) {
    for (int t2 = tid; t2 < 512; t2 += 256) { float v = A[t2]; if (t2 >= off) v += A[t2 - off]; D[t2] = v; }
    __syncthreads();
    float* tmp = A; A = D; D = tmp;
  }
  float* R = D;
  for (int t2 = tid; t2 < 512; t2 += 256) R[t2] = 1.f / A[t2];
  __syncthreads();

  const int h0 = tid * 2;
  float ax = 0.f, ay = 0.f;
  for (int t = 0; t < 512; ++t) {
    const float* hpp = histN + ((size_t)(b * Tn + t)) * Hn + h0;
    float x0 = hpp[0], x1 = hpp[1];
    float et = ee[t], rd = R[t];
    ax = fmaf(et, x0, ax); ay = fmaf(et, x1, ay);
    u32 pack = (u32)f2bf(x0 + ax * rd) | ((u32)f2bf(x1 + ay * rd) << 16);
    *(u32*)(att + ((size_t)(b * Tn + t)) * Hn + h0) = pack;
  }
}

// ---------------- final GEMM: att[2048x512]bf16 @ WhB[512xNPAD]bf16 + bh -> fp32 ----------------
typedef short bf16x8_t __attribute__((ext_vector_type(8)));
typedef float f32x4_t  __attribute__((ext_vector_type(4)));

__global__ __launch_bounds__(256) void gemm_kernel(
    const u16* __restrict__ Aw, const u16* __restrict__ Bw,
    const float* __restrict__ bh, float* __restrict__ out)
{
  __shared__ u16 Alds[128 * 64];
  __shared__ u16 Blds[64 * 128];
  const int tid = threadIdx.x;
  const int n0 = blockIdx.x * 128, m0 = blockIdx.y * 128;
  const int w = tid >> 6, lane = tid & 63;
  const int wm = (w & 1) * 64, wn = (w >> 1) * 64;

  f32x4_t acc[4][4];
  #pragma unroll
  for (int i = 0; i < 4; ++i)
    #pragma unroll
    for (int j = 0; j < 4; ++j) acc[i][j] = (f32x4_t){0.f, 0.f, 0.f, 0.f};

  for (int kt = 0; kt < 8; ++kt) {
    const int k0 = kt * 64;
    {
      int row = tid >> 1, kc = (tid & 1) * 32;
      #pragma unroll
      for (int jj = 0; jj < 4; ++jj) {
        uint4 v = *(const uint4*)(Aw + (size_t)(m0 + row) * 512 + k0 + kc + jj * 8);
        int byte = row * 128 + (kc + jj * 8) * 2;
        byte ^= (row & 7) << 4;
        *(uint4*)((char*)Alds + byte) = v;
      }
    }
    {
      #pragma unroll
      for (int q = 0; q < 4; ++q) {
        int r = (tid >> 4) + q * 16, c8 = (tid & 15) * 8;
        uint4 v = *(const uint4*)(Bw + (size_t)(k0 + r) * NPAD + n0 + c8);
        *(uint4*)&Blds[r * 128 + c8] = v;
      }
    }
    __syncthreads();
    #pragma unroll
    for (int kh = 0; kh < 2; ++kh) {
      bf16x8_t af[4];
      #pragma unroll
      for (int i = 0; i < 4; ++i) {
        int row = wm + i * 16 + (lane & 15);
        int byte = row * 128 + kh * 64 + (lane >> 4) * 16;
        byte ^= (row & 7) << 4;
        af[i] = *(const bf16x8_t*)((const char*)Alds + byte);
      }
      const int kb = kh * 32 + (lane >> 4) * 8;
      #pragma unroll
      for (int j = 0; j < 4; ++j) {
        int col = wn + j * 16 + (lane & 15);
        bf16x8_t bf;
        #pragma unroll
        for (int jj = 0; jj < 8; ++jj) bf[jj] = (short)Blds[(kb + jj) * 128 + col];
        #pragma unroll
        for (int i = 0; i < 4; ++i)
          acc[i][j] = __builtin_amdgcn_mfma_f32_16x16x32_bf16(af[i], bf, acc[i][j], 0, 0, 0);
      }
    }
    __syncthreads();
  }
  #pragma unroll
  for (int j = 0; j < 4; ++j) {
    int col = n0 + wn + j * 16 + (lane & 15);
    if (col < Vn) {
      float bias = bh[col];
      #pragma unroll
      for (int i = 0; i < 4; ++i) {
        int rbase = m0 + wm + i * 16 + (lane >> 4) * 4;
        #pragma unroll
        for (int r = 0; r < 4; ++r)
          out[(size_t)(rbase + r) * Vn + col] = acc[i][j][r] + bias;
      }
    }
  }
}

// ---------------- host ----------------
extern "C" void kernel_launch(void* const* d_in, const int* in_sizes, int n_in,
                              void* d_out, int out_size, void* d_ws, size_t ws_size,
                              hipStream_t stream) {
  const int*   ids  = (const int*)d_in[0];
  const float* emb  = (const float*)d_in[1];
  const float* Wc1_0 = (const float*)d_in[2];  const float* bc1_0 = (const float*)d_in[3];
  const float* Wc2_0 = (const float*)d_in[4];  const float* bc2_0 = (const float*)d_in[5];
  const float* Wg1_0 = (const float*)d_in[6];  const float* bg1_0 = (const float*)d_in[7];
  const float* Wg2_0 = (const float*)d_in[8];  const float* bg2_0 = (const float*)d_in[9];
  const float* Wr_0  = (const float*)d_in[10]; const float* br_0  = (const float*)d_in[11];
  const float* Wc1_1 = (const float*)d_in[12]; const float* bc1_1 = (const float*)d_in[13];
  const float* Wc2_1 = (const float*)d_in[14]; const float* bc2_1 = (const float*)d_in[15];
  const float* Wg1_1 = (const float*)d_in[16]; const float* bg1_1 = (const float*)d_in[17];
  const float* Wg2_1 = (const float*)d_in[18]; const float* bg2_1 = (const float*)d_in[19];
  const float* Wr_1  = (const float*)d_in[20]; const float* br_1  = (const float*)d_in[21];
  const float* Wa1 = (const float*)d_in[22]; const float* ba1 = (const float*)d_in[23];
  const float* Wa2 = (const float*)d_in[24]; const float* ba2 = (const float*)d_in[25];
  const float* Wh  = (const float*)d_in[26]; const float* bh  = (const float*)d_in[27];

  float* out = (float*)d_out;
  char*  ws  = (char*)d_ws;

  const size_t OFF_FLAGS = 0;                        // 16 KB
  const size_t OFF_PST   = 16384;                    // 8 KB
  const size_t OFF_HQ0   = 24576;                    // 8 KB
  const size_t OFF_HQ1   = 32768;                    // 8 KB
  const size_t OFF_CAND  = 40960;                    // 16 KB
  const size_t OFF_G1    = 57344;                    // 8 KB
  const size_t OFF_WTH   = 65536;                    // 11,534,336 B
  const size_t OFF_HISTR = OFF_WTH + 11534336;
  const size_t OFF_HISTN = OFF_HISTR + 4194304;
  const size_t OFF_SCO   = OFF_HISTN + 4194304;
  const size_t OFF_ATT   = OFF_SCO + 8192;
  const size_t OFF_WHB   = OFF_ATT + 2097152;

  u32*   flags  = (u32*)(ws + OFF_FLAGS);
  float* pstats = (float*)(ws + OFF_PST);
  float* hq0    = (float*)(ws + OFF_HQ0);
  float* hq1    = (float*)(ws + OFF_HQ1);
  float* cand1  = (float*)(ws + OFF_CAND);
  float* g1buf  = (float*)(ws + OFF_G1);
  __half* wth   = (__half*)(ws + OFF_WTH);
  float* histR  = (float*)(ws + OFF_HISTR);
  float* histN  = (float*)(ws + OFF_HISTN);
  float* scores = (float*)(ws + OFF_SCO);
  u16*   att    = (u16*)(ws + OFF_ATT);
  u16*   whb    = (u16*)(ws + OFF_WHB);
  float* gates  = out + (size_t)Bn * Tn * Vn;

  __half* wtC1_0 = wth;
  __half* wtG1_0 = wth + 1310720;
  __half* wtC2_0 = wth + 1966080;
  __half* wtR_0  = wth + 2490368;
  __half* wtC1_1 = wth + 2621440;
  __half* wtG1_1 = wth + 4194304;
  __half* wtC2_1 = wth + 4980736;
  __half* wtR_1  = wth + 5505024;

  hipMemsetAsync(ws, 0, 65536, stream);   // flags + pstats + hq + cand1 + g1

  transpose_h<<<dim3(32, 40), 256, 0, stream>>>(Wc1_0, wtC1_0, 1280, 1024);
  transpose_h<<<dim3(16, 40), 256, 0, stream>>>(Wg1_0, wtG1_0, 1280, 512);
  transpose_h<<<dim3(16, 32), 256, 0, stream>>>(Wc2_0, wtC2_0, 1024, 512);
  transpose_h<<<dim3(16,  8), 256, 0, stream>>>(Wr_0,  wtR_0,   256, 512);
  transpose_h<<<dim3(32, 48), 256, 0, stream>>>(Wc1_1, wtC1_1, 1536, 1024);
  transpose_h<<<dim3(16, 48), 256, 0, stream>>>(Wg1_1, wtG1_1, 1536, 512);
  transpose_h<<<dim3(16, 32), 256, 0, stream>>>(Wc2_1, wtC2_1, 1024, 512);
  transpose_h<<<dim3(16, 16), 256, 0, stream>>>(Wr_1,  wtR_1,   512, 512);

  convwh_kernel<<<dim3(99, 512), 256, 0, stream>>>(Wh, whb);

  (void)hipFuncSetAttribute((const void*)rec_kernel,
                            hipFuncAttributeMaxDynamicSharedMemorySize, REC_LDS);

  rec_kernel<<<dim3(RG), dim3(RNT), REC_LDS, stream>>>(
      ids, emb,
      (const u16*)wtC1_0, (const u16*)wtG1_0, (const u16*)wtC2_0, (const u16*)wtR_0,
      (const u16*)wtC1_1, (const u16*)wtG1_1, (const u16*)wtC2_1, (const u16*)wtR_1,
      bc1_0, bg1_0, bc2_0, br_0, Wg2_0, bg2_0,
      bc1_1, bg1_1, bc2_1, br_1, Wg2_1, bg2_1,
      hq0, hq1, pstats, cand1, g1buf, flags, histR, gates);

  scores_kernel<<<dim3(256), 256, 0, stream>>>(histR, Wa1, ba1, Wa2, ba2, histN, scores);

  cumsum_kernel<<<dim3(Bn), 256, 0, stream>>>(scores, histN, att);

  gemm_kernel<<<dim3(393, 16), 256, 0, stream>>>(att, whb, bh, out);
}

// Round 4
// 7253.949 us; speedup vs baseline: 5.5838x; 3.4124x over previous
//
#include <hip/hip_runtime.h>
#include <hip/hip_fp16.h>
#include <cstdint>
#include <cstddef>

typedef unsigned short u16;
typedef unsigned int   u32;
typedef unsigned long long u64;

#define Bn 4
#define Tn 512
#define Hn 512
#define En 256
#define Vn 50257
#define NPAD 50304

#define RG  128
#define GRP 64
#define RNT 256

// ---- dynamic LDS byte offsets ----
#define XB_B    98304              // fp16 weights region before this (L1 max 98304 B)
#define MI_B    122880             // XB_B + 24576
#define GATE_B  122944
#define RL_B    122960
#define HL_B    123088
#define WG2L_B  123216
#define BC1L_B  123248
#define BG1L_B  123312
#define BRL_B   123344
#define BC2L_B  123376
#define BG2L_B  123408
#define REC_LDS 123424

__device__ __forceinline__ u16 f2bf(float f) {
  u32 x; __builtin_memcpy(&x, &f, 4);
  u32 r = (x + 0x7fffu + ((x >> 16) & 1u)) >> 16;
  return (u16)r;
}

__device__ __forceinline__ float gld(const float* p) {
  return __hip_atomic_load(p, __ATOMIC_RELAXED, __HIP_MEMORY_SCOPE_AGENT);
}
__device__ __forceinline__ void gst(float* p, float v) {
  __hip_atomic_store(p, v, __ATOMIC_RELAXED, __HIP_MEMORY_SCOPE_AGENT);
}
__device__ __forceinline__ float2 gld2(const float* p) {
  u64 v = __hip_atomic_load((const u64*)p, __ATOMIC_RELAXED, __HIP_MEMORY_SCOPE_AGENT);
  float2 r;
  u32 lo = (u32)v, hi = (u32)(v >> 32);
  __builtin_memcpy(&r.x, &lo, 4); __builtin_memcpy(&r.y, &hi, 4);
  return r;
}
__device__ __forceinline__ void gst2(float* p, float a, float b) {
  u32 la, lb; __builtin_memcpy(&la, &a, 4); __builtin_memcpy(&lb, &b, 4);
  u64 v = ((u64)lb << 32) | la;
  __hip_atomic_store((u64*)p, v, __ATOMIC_RELAXED, __HIP_MEMORY_SCOPE_AGENT);
}

// flag-broadcast grid barrier: own-slot store + all-poll
__device__ __forceinline__ void gbar(u32* flags, unsigned& ep, int g) {
  ++ep;
  asm volatile("s_waitcnt vmcnt(0)" ::: "memory");
  __syncthreads();
  if (threadIdx.x == 0)
    __hip_atomic_store(&flags[g * 4], ep, __ATOMIC_RELAXED, __HIP_MEMORY_SCOPE_AGENT);
  if (threadIdx.x < 64) {
    bool wait_;
    do {
      u32 a = __hip_atomic_load(&flags[threadIdx.x * 4], __ATOMIC_RELAXED, __HIP_MEMORY_SCOPE_AGENT);
      u32 b = __hip_atomic_load(&flags[(threadIdx.x + 64) * 4], __ATOMIC_RELAXED, __HIP_MEMORY_SCOPE_AGENT);
      wait_ = (a < ep) || (b < ep);
    } while (__any(wait_));
  }
  __syncthreads();
}

// ---------------- transpose + fp32->fp16: dst[n*K+k] = (half)src[k*N+n] ----------------
__global__ __launch_bounds__(256) void transpose_h(
    const float* __restrict__ src, __half* __restrict__ dst, int K, int N)
{
  __shared__ float tile[32][33];
  const int tx = threadIdx.x & 31, ty = threadIdx.x >> 5;
  const int bn = blockIdx.x * 32, bk = blockIdx.y * 32;
  #pragma unroll
  for (int i = 0; i < 4; ++i)
    tile[ty + i * 8][tx] = src[(size_t)(bk + ty + i * 8) * N + bn + tx];
  __syncthreads();
  #pragma unroll
  for (int i = 0; i < 4; ++i)
    dst[(size_t)(bn + ty + i * 8) * K + bk + tx] = __float2half(tile[tx][ty + i * 8]);
}

// ---------------- Wh fp32 -> bf16 padded [512][NPAD] ----------------
__global__ __launch_bounds__(256) void convwh_kernel(
    const float* __restrict__ wh, u16* __restrict__ whb)
{
  const int k = blockIdx.y;
  const int v0 = (blockIdx.x * 256 + threadIdx.x) * 2;
  if (v0 >= NPAD) return;
  float a = (v0     < Vn) ? wh[(size_t)k * Vn + v0]     : 0.f;
  float b = (v0 + 1 < Vn) ? wh[(size_t)k * Vn + v0 + 1] : 0.f;
  u32 pack = (u32)f2bf(a) | ((u32)f2bf(b) << 16);
  *(u32*)&whb[(size_t)k * NPAD + v0] = pack;
}

// ---------------- persistent recurrence: layer-pipelined ----------------
// blocks 0..63: layer 0 at t=tick ; blocks 64..127: layer 1 at t=tick-1
__global__ __launch_bounds__(RNT, 1) void rec_kernel(
    const int* __restrict__ ids, const float* __restrict__ emb,
    const __half* __restrict__ wtC1_0, const __half* __restrict__ wtG1_0,
    const __half* __restrict__ wtC2_0, const __half* __restrict__ wtR_0,
    const __half* __restrict__ wtC1_1, const __half* __restrict__ wtG1_1,
    const __half* __restrict__ wtC2_1, const __half* __restrict__ wtR_1,
    const float* __restrict__ bc1_0, const float* __restrict__ bg1_0,
    const float* __restrict__ bc2_0, const float* __restrict__ br_0,
    const float* __restrict__ wg2_0, const float* __restrict__ bg2_0,
    const float* __restrict__ bc1_1, const float* __restrict__ bg1_1,
    const float* __restrict__ bc2_1, const float* __restrict__ br_1,
    const float* __restrict__ wg2_1, const float* __restrict__ bg2_1,
    float* __restrict__ hq0, float* __restrict__ hq1,
    float* __restrict__ pstats, float* __restrict__ gpart,
    float* __restrict__ cand0, float* __restrict__ cand1,
    u32* flags, float* __restrict__ histR, float* __restrict__ gates_out)
{
  extern __shared__ char smem[];
  __half* WL   = (__half*)smem;
  float* xbl   = (float*)(smem + XB_B);     // [4][1536]
  float* mi    = (float*)(smem + MI_B);     // h1: m[4] i[4] ; inp: m[4] i[4]
  float* gateL = (float*)(smem + GATE_B);
  float* rloc  = (float*)(smem + RL_B);     // [8 c][4 b]
  float* hloc  = (float*)(smem + HL_B);     // [8 c][4 b]
  float* wg2loc= (float*)(smem + WG2L_B);
  float* bc1loc= (float*)(smem + BC1L_B);
  float* bg1loc= (float*)(smem + BG1L_B);
  float* brloc = (float*)(smem + BRL_B);
  float* bc2loc= (float*)(smem + BC2L_B);
  float* bg2loc= (float*)(smem + BG2L_B);

  const int tid = threadIdx.x, g = blockIdx.x;
  const int l = g >> 6, gl = g & 63;
  const int w = tid >> 6, lane = tid & 63;
  const int C = l ? 1536 : 1280;
  const int e = l ? 512 : 256;
  const int oG1 = 16 * C, oR = 24 * C, oC2 = 24 * C + 8 * e;

  const __half* wtC1 = l ? wtC1_1 : wtC1_0;
  const __half* wtG1 = l ? wtG1_1 : wtG1_0;
  const __half* wtC2 = l ? wtC2_1 : wtC2_0;
  const __half* wtR  = l ? wtR_1  : wtR_0;
  const float* bc1 = l ? bc1_1 : bc1_0;
  const float* bg1 = l ? bg1_1 : bg1_0;
  const float* bc2 = l ? bc2_1 : bc2_0;
  const float* br  = l ? br_1  : br_0;
  const float* wg2 = l ? wg2_1 : wg2_0;
  const float* bg2 = l ? bg2_1 : bg2_0;
  float* hq  = l ? hq1 : hq0;
  float* cnd = l ? cand1 : cand0;

  // ---- one-time staging of this block's weight slice ----
  {
    auto cp = [&](const __half* src, int nh, int off) {
      const u32* s = (const u32*)src; u32* d = (u32*)(WL + off);
      for (int p = tid; p < (nh >> 1); p += RNT) d[p] = s[p];
    };
    cp(wtC1 + (size_t)(gl * 16) * C, 16 * C, 0);
    cp(wtG1 + (size_t)(gl * 8) * C,  8 * C, oG1);
    cp(wtR  + (size_t)(gl * 8) * e,  8 * e, oR);
    cp(wtC2 + (size_t)(gl * 8) * 1024, 8 * 1024, oC2);
  }
  if (tid < 16) bc1loc[tid] = bc1[gl * 16 + tid];
  else if (tid >= 32 && tid < 40)  bg1loc[tid - 32] = bg1[gl * 8 + tid - 32];
  else if (tid >= 64 && tid < 72)  brloc[tid - 64]  = br[gl * 8 + tid - 64];
  else if (tid >= 96 && tid < 104) bc2loc[tid - 96] = bc2[gl * 8 + tid - 96];
  else if (tid >= 128 && tid < 136) wg2loc[tid - 128] = wg2[gl * 8 + tid - 128];
  else if (tid == 160) bg2loc[0] = bg2[0];
  for (int i = tid; i < 6144; i += RNT) xbl[i] = 0.f;
  __syncthreads();

  unsigned ep = 0;

  for (int tick = 0; tick <= Tn; ++tick) {
    const int t = l ? (tick - 1) : tick;
    const bool act = (t >= 0) && (t < Tn);

    // ================= Phase A =================
    // --- early global loads (one overlapped round trip) ---
    float2 h1r[4]; float2 inr[4]; float embv[4];
    #pragma unroll
    for (int q = 0; q < 4; ++q) { h1r[q] = make_float2(0.f, 0.f); inr[q] = make_float2(0.f, 0.f); embv[q] = 0.f; }
    if (t >= 1) {
      h1r[0] = gld2(hq + tid * 4);         h1r[1] = gld2(hq + tid * 4 + 2);
      h1r[2] = gld2(hq + (tid + 256) * 4); h1r[3] = gld2(hq + (tid + 256) * 4 + 2);
    }
    if (l) {
      if (act) {
        inr[0] = gld2(hq0 + tid * 4);         inr[1] = gld2(hq0 + tid * 4 + 2);
        inr[2] = gld2(hq0 + (tid + 256) * 4); inr[3] = gld2(hq0 + (tid + 256) * 4 + 2);
      }
    } else if (act) {
      #pragma unroll
      for (int q = 0; q < 4; ++q) {
        int idx = tid + q * 256, b = idx >> 8, k = idx & 255;
        int id = ids[b * Tn + t];                      // cached (immutable input)
        embv[q] = emb[(size_t)id * En + k];            // cached
      }
    }
    float2 pown = gld2(pstats + (l * GRP + lane) * 8 + w * 2);
    float2 pinp = make_float2(0.f, 0.f);
    if (l) pinp = gld2(pstats + lane * 8 + w * 2);

    // --- stats butterflies (while data loads are in flight) ---
    #pragma unroll
    for (int off = 32; off; off >>= 1) {
      pown.x += __shfl_xor(pown.x, off); pown.y += __shfl_xor(pown.y, off);
      pinp.x += __shfl_xor(pinp.x, off); pinp.y += __shfl_xor(pinp.y, off);
    }
    if (lane == 0) {
      float m = pown.x * (1.f / 512.f);
      float var = pown.y * (1.f / 512.f) - m * m;
      mi[w] = m; mi[4 + w] = rsqrtf(var + 1e-5f);
      m = pinp.x * (1.f / 512.f);
      var = pinp.y * (1.f / 512.f) - m * m;
      mi[8 + w] = m; mi[12 + w] = rsqrtf(var + 1e-5f);
    }
    __syncthreads();

    // --- stage ctx: shift h1->h2, write LN(h1), write inp ---
    #pragma unroll
    for (int jj = 0; jj < 2; ++jj) {
      int j = tid + jj * 256;
      float raw[4] = {h1r[jj * 2].x, h1r[jj * 2].y, h1r[jj * 2 + 1].x, h1r[jj * 2 + 1].y};
      #pragma unroll
      for (int b = 0; b < 4; ++b) {
        float* row = xbl + b * 1536;
        float old = row[j];
        row[512 + j] = old;
        row[j] = (t >= 1) ? (raw[b] - mi[b]) * mi[4 + b] : 0.f;
      }
    }
    if (l) {
      #pragma unroll
      for (int jj = 0; jj < 2; ++jj) {
        int j = tid + jj * 256;
        float raw[4] = {inr[jj * 2].x, inr[jj * 2].y, inr[jj * 2 + 1].x, inr[jj * 2 + 1].y};
        #pragma unroll
        for (int b = 0; b < 4; ++b)
          xbl[b * 1536 + 1024 + j] = act ? (raw[b] - mi[8 + b]) * mi[12 + b] : 0.f;
      }
    } else {
      #pragma unroll
      for (int q = 0; q < 4; ++q) {
        int idx = tid + q * 256, b = idx >> 8, k = idx & 255;
        xbl[b * 1536 + 1024 + k] = act ? embv[q] : 0.f;
      }
    }
    __syncthreads();

    // --- matvecs from LDS; 8 cols per wave ---
    {
      const __half* wb; int Kh, xo;
      if (w < 2)       { wb = WL + w * 8 * C; Kh = C; xo = 0; }
      else if (w == 2) { wb = WL + oG1;       Kh = C; xo = 0; }
      else             { wb = WL + oR;        Kh = e; xo = 1024; }
      float acc[8][4];
      #pragma unroll
      for (int c = 0; c < 8; ++c)
        #pragma unroll
        for (int b = 0; b < 4; ++b) acc[c][b] = 0.f;
      for (int p = lane; p < (Kh >> 1); p += 64) {
        float2 xv[4];
        #pragma unroll
        for (int b = 0; b < 4; ++b) xv[b] = *(const float2*)(xbl + b * 1536 + xo + 2 * p);
        #pragma unroll
        for (int c = 0; c < 8; ++c) {
          __half2 hw = *(const __half2*)(wb + c * Kh + 2 * p);
          float2 wf = __half22float2(hw);
          #pragma unroll
          for (int b = 0; b < 4; ++b)
            acc[c][b] = fmaf(wf.x, xv[b].x, fmaf(wf.y, xv[b].y, acc[c][b]));
        }
      }
      #pragma unroll
      for (int off = 32; off; off >>= 1)
        #pragma unroll
        for (int c = 0; c < 8; ++c)
          #pragma unroll
          for (int b = 0; b < 4; ++b) acc[c][b] += __shfl_xor(acc[c][b], off);

      if (w < 2) {
        if (lane < 8) {
          int c = lane, jc = gl * 16 + w * 8 + c;
          float bb = bc1loc[w * 8 + c];
          float v0 = fmaxf(acc[c][0] + bb, 0.f), v1 = fmaxf(acc[c][1] + bb, 0.f);
          float v2 = fmaxf(acc[c][2] + bb, 0.f), v3 = fmaxf(acc[c][3] + bb, 0.f);
          gst2(cnd + jc * 4, v0, v1); gst2(cnd + jc * 4 + 2, v2, v3);
        }
      } else if (w == 2) {
        if (lane < 32) {
          int c = lane >> 2, b = lane & 3;
          float v = tanhf(acc[c][b] + bg1loc[c]) * wg2loc[c];
          v += __shfl_xor(v, 4); v += __shfl_xor(v, 8); v += __shfl_xor(v, 16);
          if (c == 0) gst(gpart + (l * 4 + b) * GRP + gl, v);
        }
      } else {
        if (lane < 32) { int c = lane >> 2, b = lane & 3; rloc[c * 4 + b] = acc[c][b] + brloc[c]; }
      }
    }
    gbar(flags, ep, g);

    // ================= Phase B =================
    float2 cv[8];
    #pragma unroll
    for (int q = 0; q < 4; ++q) {
      int kk = tid + q * 256;
      cv[2 * q]     = gld2(cnd + kk * 4);
      cv[2 * q + 1] = gld2(cnd + kk * 4 + 2);
    }
    float gp = gld(gpart + (l * 4 + w) * GRP + lane);
    #pragma unroll
    for (int q = 0; q < 4; ++q) {
      int kk = tid + q * 256;
      xbl[0 * 1536 + 512 + kk] = cv[2 * q].x;
      xbl[1 * 1536 + 512 + kk] = cv[2 * q].y;
      xbl[2 * 1536 + 512 + kk] = cv[2 * q + 1].x;
      xbl[3 * 1536 + 512 + kk] = cv[2 * q + 1].y;
    }
    #pragma unroll
    for (int off = 32; off; off >>= 1) gp += __shfl_xor(gp, off);
    if (lane == 0) gateL[w] = 1.f / (1.f + expf(-(gp + bg2loc[0])));
    __syncthreads();

    {
      float a2[2][4];
      #pragma unroll
      for (int c = 0; c < 2; ++c)
        #pragma unroll
        for (int b = 0; b < 4; ++b) a2[c][b] = 0.f;
      const __half* wb2 = WL + oC2 + (size_t)(2 * w) * 1024;
      for (int p = lane; p < 512; p += 64) {
        float2 xv[4];
        #pragma unroll
        for (int b = 0; b < 4; ++b) xv[b] = *(const float2*)(xbl + b * 1536 + 512 + 2 * p);
        #pragma unroll
        for (int c = 0; c < 2; ++c) {
          __half2 hw = *(const __half2*)(wb2 + c * 1024 + 2 * p);
          float2 wf = __half22float2(hw);
          #pragma unroll
          for (int b = 0; b < 4; ++b)
            a2[c][b] = fmaf(wf.x, xv[b].x, fmaf(wf.y, xv[b].y, a2[c][b]));
        }
      }
      #pragma unroll
      for (int off = 32; off; off >>= 1)
        #pragma unroll
        for (int c = 0; c < 2; ++c)
          #pragma unroll
          for (int b = 0; b < 4; ++b) a2[c][b] += __shfl_xor(a2[c][b], off);

      if (lane < 8) {
        int c2 = lane >> 2, b = lane & 3;
        int c = 2 * w + c2, j = gl * 8 + c;
        float cand = a2[c2][b] + bc2loc[c];
        float hv = xbl[b * 1536 + j] + gateL[b] * cand + 0.1f * rloc[c * 4 + b];
        hloc[c * 4 + b] = hv;
        if (act) gst(hq + j * 4 + b, hv);
      }
    }
    __syncthreads();
    if (act) {
      if (tid < 32) {
        int c = tid >> 2, b = tid & 3;
        float v = hloc[c * 4 + b];
        float s = v, ss = v * v;
        s += __shfl_xor(s, 4);  ss += __shfl_xor(ss, 4);
        s += __shfl_xor(s, 8);  ss += __shfl_xor(ss, 8);
        s += __shfl_xor(s, 16); ss += __shfl_xor(ss, 16);
        if (c == 0) gst2(pstats + (l * GRP + gl) * 8 + b * 2, s, ss);
      }
      if (l) {
        if (tid >= 64 && tid < 96) {
          int q = tid - 64, b = q >> 3, c = q & 7;
          gst(histR + ((size_t)b * Tn + t) * Hn + gl * 8 + c, hloc[c * 4 + b]);
        }
        if (gl == 0 && tid >= 128 && tid < 132)
          gst(gates_out + (tid - 128) * Tn + t, gateL[tid - 128]);
      }
    }
    gbar(flags, ep, g);
  }
}

// ---------------- attention scores (+ histN = LN(histR)) ----------------
__global__ __launch_bounds__(256) void scores_kernel(
    const float* __restrict__ histR,
    const float* __restrict__ wa1, const float* __restrict__ ba1,
    const float* __restrict__ wa2, const float* __restrict__ ba2,
    float* __restrict__ histN, float* __restrict__ scores)
{
  __shared__ float xs[8][512];
  __shared__ float mm[8], ii[8];
  __shared__ float wacc[4][8];
  const int tid = threadIdx.x, bid = blockIdx.x;

  for (int idx = tid; idx < 4096; idx += 256)
    xs[idx >> 9][idx & 511] = histR[(size_t)(bid * 8) * Hn + idx];
  __syncthreads();
  {
    int r = tid >> 5, i = tid & 31;
    float s = 0.f, ss = 0.f;
    for (int k = i; k < 512; k += 32) { float v = xs[r][k]; s += v; ss += v * v; }
    #pragma unroll
    for (int off = 16; off; off >>= 1) { s += __shfl_xor(s, off); ss += __shfl_xor(ss, off); }
    if (i == 0) {
      float m = s * (1.f / Hn);
      float var = ss * (1.f / Hn) - m * m;
      mm[r] = m; ii[r] = rsqrtf(var + 1e-5f);
    }
  }
  __syncthreads();
  for (int idx = tid; idx < 4096; idx += 256) {
    int r = idx >> 9, k = idx & 511;
    float x = (xs[r][k] - mm[r]) * ii[r];
    xs[r][k] = x;
    histN[(size_t)(bid * 8) * Hn + idx] = x;
  }
  __syncthreads();

  float pr[8] = {0.f, 0.f, 0.f, 0.f, 0.f, 0.f, 0.f, 0.f};
  #pragma unroll
  for (int cc = 0; cc < 2; ++cc) {
    int c = tid + cc * 256;
    float a[8] = {0.f, 0.f, 0.f, 0.f, 0.f, 0.f, 0.f, 0.f};
    for (int k = 0; k < 512; ++k) {
      float wv = wa1[(size_t)k * 512 + c];
      #pragma unroll
      for (int r = 0; r < 8; ++r) a[r] = fmaf(xs[r][k], wv, a[r]);
    }
    float b1 = ba1[c], w2 = wa2[c];
    #pragma unroll
    for (int r = 0; r < 8; ++r) pr[r] += tanhf(a[r] + b1) * w2;
  }
  int lane = tid & 63, wq = tid >> 6;
  #pragma unroll
  for (int off = 32; off; off >>= 1)
    #pragma unroll
    for (int r = 0; r < 8; ++r) pr[r] += __shfl_xor(pr[r], off);
  if (lane == 0) {
    #pragma unroll
    for (int r = 0; r < 8; ++r) wacc[wq][r] = pr[r];
  }
  __syncthreads();
  if (tid < 8)
    scores[bid * 8 + tid] = wacc[0][tid] + wacc[1][tid] + wacc[2][tid] + wacc[3][tid] + ba2[0];
}

// ---------------- prefix-softmax cumsum -> attended (bf16) ----------------
__global__ __launch_bounds__(256) void cumsum_kernel(
    const float* __restrict__ scores, const float* __restrict__ histN,
    u16* __restrict__ att)
{
  __shared__ float ee[512], den[512], sb[512], red[256];
  const int tid = threadIdx.x, b = blockIdx.x;
  float s0 = scores[b * Tn + tid], s1 = scores[b * Tn + tid + 256];
  red[tid] = fmaxf(s0, s1);
  __syncthreads();
  for (int s = 128; s; s >>= 1) { if (tid < s) red[tid] = fmaxf(red[tid], red[tid + s]); __syncthreads(); }
  float m = red[0];
  ee[tid] = expf(s0 - m); ee[tid + 256] = expf(s1 - m);
  den[tid] = ee[tid]; den[tid + 256] = ee[tid + 256];
  __syncthreads();
  float* A = den; float* D = sb;
  for (int off = 1; off < 512; off <<= 1) {
    for (int t2 = tid; t2 < 512; t2 += 256) { float v = A[t2]; if (t2 >= off) v += A[t2 - off]; D[t2] = v; }
    __syncthreads();
    float* tmp = A; A = D; D = tmp;
  }
  float* R = D;
  for (int t2 = tid; t2 < 512; t2 += 256) R[t2] = 1.f / A[t2];
  __syncthreads();

  const int h0 = tid * 2;
  float ax = 0.f, ay = 0.f;
  for (int t = 0; t < 512; ++t) {
    const float* hpp = histN + ((size_t)(b * Tn + t)) * Hn + h0;
    float x0 = hpp[0], x1 = hpp[1];
    float et = ee[t], rd = R[t];
    ax = fmaf(et, x0, ax); ay = fmaf(et, x1, ay);
    u32 pack = (u32)f2bf(x0 + ax * rd) | ((u32)f2bf(x1 + ay * rd) << 16);
    *(u32*)(att + ((size_t)(b * Tn + t)) * Hn + h0) = pack;
  }
}

// ---------------- final GEMM: att[2048x512]bf16 @ WhB[512xNPAD]bf16 + bh -> fp32 ----------------
typedef short bf16x8_t __attribute__((ext_vector_type(8)));
typedef float f32x4_t  __attribute__((ext_vector_type(4)));

__global__ __launch_bounds__(256) void gemm_kernel(
    const u16* __restrict__ Aw, const u16* __restrict__ Bw,
    const float* __restrict__ bh, float* __restrict__ out)
{
  __shared__ u16 Alds[128 * 64];
  __shared__ u16 Blds[64 * 128];
  const int tid = threadIdx.x;
  const int n0 = blockIdx.x * 128, m0 = blockIdx.y * 128;
  const int w = tid >> 6, lane = tid & 63;
  const int wm = (w & 1) * 64, wn = (w >> 1) * 64;

  f32x4_t acc[4][4];
  #pragma unroll
  for (int i = 0; i < 4; ++i)
    #pragma unroll
    for (int j = 0; j < 4; ++j) acc[i][j] = (f32x4_t){0.f, 0.f, 0.f, 0.f};

  for (int kt = 0; kt < 8; ++kt) {
    const int k0 = kt * 64;
    {
      int row = tid >> 1, kc = (tid & 1) * 32;
      #pragma unroll
      for (int jj = 0; jj < 4; ++jj) {
        uint4 v = *(const uint4*)(Aw + (size_t)(m0 + row) * 512 + k0 + kc + jj * 8);
        int byte = row * 128 + (kc + jj * 8) * 2;
        byte ^= (row & 7) << 4;
        *(uint4*)((char*)Alds + byte) = v;
      }
    }
    {
      #pragma unroll
      for (int q = 0; q < 4; ++q) {
        int r = (tid >> 4) + q * 16, c8 = (tid & 15) * 8;
        uint4 v = *(const uint4*)(Bw + (size_t)(k0 + r) * NPAD + n0 + c8);
        *(uint4*)&Blds[r * 128 + c8] = v;
      }
    }
    __syncthreads();
    #pragma unroll
    for (int kh = 0; kh < 2; ++kh) {
      bf16x8_t af[4];
      #pragma unroll
      for (int i = 0; i < 4; ++i) {
        int row = wm + i * 16 + (lane & 15);
        int byte = row * 128 + kh * 64 + (lane >> 4) * 16;
        byte ^= (row & 7) << 4;
        af[i] = *(const bf16x8_t*)((const char*)Alds + byte);
      }
      const int kb = kh * 32 + (lane >> 4) * 8;
      #pragma unroll
      for (int j = 0; j < 4; ++j) {
        int col = wn + j * 16 + (lane & 15);
        bf16x8_t bf;
        #pragma unroll
        for (int jj = 0; jj < 8; ++jj) bf[jj] = (short)Blds[(kb + jj) * 128 + col];
        #pragma unroll
        for (int i = 0; i < 4; ++i)
          acc[i][j] = __builtin_amdgcn_mfma_f32_16x16x32_bf16(af[i], bf, acc[i][j], 0, 0, 0);
      }
    }
    __syncthreads();
  }
  #pragma unroll
  for (int j = 0; j < 4; ++j) {
    int col = n0 + wn + j * 16 + (lane & 15);
    if (col < Vn) {
      float bias = bh[col];
      #pragma unroll
      for (int i = 0; i < 4; ++i) {
        int rbase = m0 + wm + i * 16 + (lane >> 4) * 4;
        #pragma unroll
        for (int r = 0; r < 4; ++r)
          out[(size_t)(rbase + r) * Vn + col] = acc[i][j][r] + bias;
      }
    }
  }
}

// ---------------- host ----------------
extern "C" void kernel_launch(void* const* d_in, const int* in_sizes, int n_in,
                              void* d_out, int out_size, void* d_ws, size_t ws_size,
                              hipStream_t stream) {
  const int*   ids  = (const int*)d_in[0];
  const float* emb  = (const float*)d_in[1];
  const float* Wc1_0 = (const float*)d_in[2];  const float* bc1_0 = (const float*)d_in[3];
  const float* Wc2_0 = (const float*)d_in[4];  const float* bc2_0 = (const float*)d_in[5];
  const float* Wg1_0 = (const float*)d_in[6];  const float* bg1_0 = (const float*)d_in[7];
  const float* Wg2_0 = (const float*)d_in[8];  const float* bg2_0 = (const float*)d_in[9];
  const float* Wr_0  = (const float*)d_in[10]; const float* br_0  = (const float*)d_in[11];
  const float* Wc1_1 = (const float*)d_in[12]; const float* bc1_1 = (const float*)d_in[13];
  const float* Wc2_1 = (const float*)d_in[14]; const float* bc2_1 = (const float*)d_in[15];
  const float* Wg1_1 = (const float*)d_in[16]; const float* bg1_1 = (const float*)d_in[17];
  const float* Wg2_1 = (const float*)d_in[18]; const float* bg2_1 = (const float*)d_in[19];
  const float* Wr_1  = (const float*)d_in[20]; const float* br_1  = (const float*)d_in[21];
  const float* Wa1 = (const float*)d_in[22]; const float* ba1 = (const float*)d_in[23];
  const float* Wa2 = (const float*)d_in[24]; const float* ba2 = (const float*)d_in[25];
  const float* Wh  = (const float*)d_in[26]; const float* bh  = (const float*)d_in[27];

  float* out = (float*)d_out;
  char*  ws  = (char*)d_ws;

  const size_t OFF_FLAGS = 0;                         // 2 KB
  const size_t OFF_PST   = 4096;                      // 4 KB
  const size_t OFF_GPART = 8192;                      // 2 KB
  const size_t OFF_HQ0   = 12288;                     // 8 KB
  const size_t OFF_HQ1   = 20480;                     // 8 KB
  const size_t OFF_CAND0 = 28672;                     // 16 KB
  const size_t OFF_CAND1 = 45056;                     // 16 KB -> 61440
  const size_t OFF_WTH   = 65536;                     // 11,534,336 B
  const size_t OFF_HISTR = OFF_WTH + 11534336;
  const size_t OFF_HISTN = OFF_HISTR + 4194304;
  const size_t OFF_SCO   = OFF_HISTN + 4194304;
  const size_t OFF_ATT   = OFF_SCO + 8192;
  const size_t OFF_WHB   = OFF_ATT + 2097152;

  u32*   flags  = (u32*)(ws + OFF_FLAGS);
  float* pstats = (float*)(ws + OFF_PST);
  float* gpart  = (float*)(ws + OFF_GPART);
  float* hq0    = (float*)(ws + OFF_HQ0);
  float* hq1    = (float*)(ws + OFF_HQ1);
  float* cand0  = (float*)(ws + OFF_CAND0);
  float* cand1  = (float*)(ws + OFF_CAND1);
  __half* wth   = (__half*)(ws + OFF_WTH);
  float* histR  = (float*)(ws + OFF_HISTR);
  float* histN  = (float*)(ws + OFF_HISTN);
  float* scores = (float*)(ws + OFF_SCO);
  u16*   att    = (u16*)(ws + OFF_ATT);
  u16*   whb    = (u16*)(ws + OFF_WHB);
  float* gates  = out + (size_t)Bn * Tn * Vn;

  __half* wtC1_0 = wth;
  __half* wtG1_0 = wth + 1310720;
  __half* wtC2_0 = wth + 1966080;
  __half* wtR_0  = wth + 2490368;
  __half* wtC1_1 = wth + 2621440;
  __half* wtG1_1 = wth + 4194304;
  __half* wtC2_1 = wth + 4980736;
  __half* wtR_1  = wth + 5505024;

  hipMemsetAsync(ws, 0, 61440, stream);

  transpose_h<<<dim3(32, 40), 256, 0, stream>>>(Wc1_0, wtC1_0, 1280, 1024);
  transpose_h<<<dim3(16, 40), 256, 0, stream>>>(Wg1_0, wtG1_0, 1280, 512);
  transpose_h<<<dim3(16, 32), 256, 0, stream>>>(Wc2_0, wtC2_0, 1024, 512);
  transpose_h<<<dim3(16,  8), 256, 0, stream>>>(Wr_0,  wtR_0,   256, 512);
  transpose_h<<<dim3(32, 48), 256, 0, stream>>>(Wc1_1, wtC1_1, 1536, 1024);
  transpose_h<<<dim3(16, 48), 256, 0, stream>>>(Wg1_1, wtG1_1, 1536, 512);
  transpose_h<<<dim3(16, 32), 256, 0, stream>>>(Wc2_1, wtC2_1, 1024, 512);
  transpose_h<<<dim3(16, 16), 256, 0, stream>>>(Wr_1,  wtR_1,   512, 512);

  convwh_kernel<<<dim3(99, 512), 256, 0, stream>>>(Wh, whb);

  (void)hipFuncSetAttribute((const void*)rec_kernel,
                            hipFuncAttributeMaxDynamicSharedMemorySize, REC_LDS);

  rec_kernel<<<dim3(RG), dim3(RNT), REC_LDS, stream>>>(
      ids, emb,
      wtC1_0, wtG1_0, wtC2_0, wtR_0, wtC1_1, wtG1_1, wtC2_1, wtR_1,
      bc1_0, bg1_0, bc2_0, br_0, Wg2_0, bg2_0,
      bc1_1, bg1_1, bc2_1, br_1, Wg2_1, bg2_1,
      hq0, hq1, pstats, gpart, cand0, cand1, flags, histR, gates);

  scores_kernel<<<dim3(256), 256, 0, stream>>>(histR, Wa1, ba1, Wa2, ba2, histN, scores);

  cumsum_kernel<<<dim3(Bn), 256, 0, stream>>>(scores, histN, att);

  gemm_kernel<<<dim3(393, 16), 256, 0, stream>>>(att, whb, bh, out);
}